// Round 1
// baseline (1392.214 us; speedup 1.0000x reference)
//
#include <hip/hip_runtime.h>
#include <math.h>

#define NFEAT 512
#define NHID  128
#define NCLASS 40

// ---------------------------------------------------------------------------
// GEMM1: Y[n,128] = X[n,512] @ W[512,128]   (f32, LDS-tiled, 64x128 tile)
// ---------------------------------------------------------------------------
__global__ __launch_bounds__(256) void gemm1_kernel(const float* __restrict__ X,
                                                    const float* __restrict__ W,
                                                    float* __restrict__ Y, int n) {
  __shared__ float xs[64][36];     // 64 rows x 32 k (+4 pad, float4-aligned)
  __shared__ float wsh[32][128];   // 32 k x 128 cols
  const int tid = threadIdx.x;
  const int tx = tid & 15;         // col group: cols tx*8 .. tx*8+7
  const int ty = tid >> 4;         // row group: rows ty*4 .. ty*4+3
  const int row0 = blockIdx.x * 64;

  float acc[4][8];
#pragma unroll
  for (int i = 0; i < 4; ++i)
#pragma unroll
    for (int j = 0; j < 8; ++j) acc[i][j] = 0.f;

  const float4* X4 = (const float4*)X;
  const float4* W4 = (const float4*)W;

  for (int k0 = 0; k0 < NFEAT; k0 += 32) {
    // stage X tile: 64x32 floats = 512 float4, 2 per thread (coalesced)
#pragma unroll
    for (int i = 0; i < 2; ++i) {
      int p = tid + i * 256;
      int m = p >> 3, q = p & 7;
      int gr = row0 + m;
      float4 v = make_float4(0.f, 0.f, 0.f, 0.f);
      if (gr < n) v = X4[gr * (NFEAT / 4) + (k0 >> 2) + q];
      *(float4*)&xs[m][q * 4] = v;
    }
    // stage W tile: 32x128 floats = 1024 float4, 4 per thread (coalesced)
#pragma unroll
    for (int i = 0; i < 4; ++i) {
      int p = tid + i * 256;
      int kk = p >> 5, qq = p & 31;
      *(float4*)&wsh[kk][qq * 4] = W4[(k0 + kk) * (NHID / 4) + qq];
    }
    __syncthreads();
#pragma unroll
    for (int k = 0; k < 32; ++k) {
      float a[4];
#pragma unroll
      for (int i = 0; i < 4; ++i) a[i] = xs[ty * 4 + i][k];
      float b[8];
#pragma unroll
      for (int j = 0; j < 8; ++j) b[j] = wsh[k][tx * 8 + j];
#pragma unroll
      for (int i = 0; i < 4; ++i)
#pragma unroll
        for (int j = 0; j < 8; ++j) acc[i][j] = fmaf(a[i], b[j], acc[i][j]);
    }
    __syncthreads();
  }
  float4* Y4 = (float4*)Y;
#pragma unroll
  for (int i = 0; i < 4; ++i) {
    int gr = row0 + ty * 4 + i;
    if (gr < n) {
      float4 o0 = make_float4(acc[i][0], acc[i][1], acc[i][2], acc[i][3]);
      float4 o1 = make_float4(acc[i][4], acc[i][5], acc[i][6], acc[i][7]);
      Y4[gr * (NHID / 4) + tx * 2] = o0;
      Y4[gr * (NHID / 4) + tx * 2 + 1] = o1;
    }
  }
}

// ---------------------------------------------------------------------------
// CSR build: count -> scan -> fill
// ---------------------------------------------------------------------------
__global__ void count_kernel(const int* __restrict__ erow, int* __restrict__ cnt, int e) {
  int i = blockIdx.x * 256 + threadIdx.x;
  if (i < e) atomicAdd(&cnt[erow[i]], 1);
}

// block-level exclusive scan: 1024 elems/block (256 thr x 4)
__global__ __launch_bounds__(256) void scanA_kernel(const int* __restrict__ cnt,
                                                    int* __restrict__ part,
                                                    int* __restrict__ bsum, int n) {
  __shared__ int s[256];
  const int tid = threadIdx.x;
  const int base = blockIdx.x * 1024 + tid * 4;
  int v0 = (base + 0 < n) ? cnt[base + 0] : 0;
  int v1 = (base + 1 < n) ? cnt[base + 1] : 0;
  int v2 = (base + 2 < n) ? cnt[base + 2] : 0;
  int v3 = (base + 3 < n) ? cnt[base + 3] : 0;
  int tsum = v0 + v1 + v2 + v3;
  s[tid] = tsum;
  __syncthreads();
  for (int off = 1; off < 256; off <<= 1) {
    int x = (tid >= off) ? s[tid - off] : 0;
    __syncthreads();
    s[tid] += x;
    __syncthreads();
  }
  int excl = s[tid] - tsum;  // exclusive prefix for this thread within block
  if (base + 0 < n) part[base + 0] = excl;
  if (base + 1 < n) part[base + 1] = excl + v0;
  if (base + 2 < n) part[base + 2] = excl + v0 + v1;
  if (base + 3 < n) part[base + 3] = excl + v0 + v1 + v2;
  if (tid == 255) bsum[blockIdx.x] = s[255];
}

__global__ __launch_bounds__(256) void scanB_kernel(int* __restrict__ bsum, int nb) {
  __shared__ int s[256];
  const int tid = threadIdx.x;
  int own = (tid < nb) ? bsum[tid] : 0;
  s[tid] = own;
  __syncthreads();
  for (int off = 1; off < 256; off <<= 1) {
    int x = (tid >= off) ? s[tid - off] : 0;
    __syncthreads();
    s[tid] += x;
    __syncthreads();
  }
  if (tid < nb) bsum[tid] = s[tid] - own;  // exclusive
}

__global__ void scanC_kernel(int* __restrict__ offs, const int* __restrict__ bsum,
                             int* __restrict__ cursor, int n, int e) {
  int i = blockIdx.x * 256 + threadIdx.x;
  if (i < n) {
    int v = offs[i] + bsum[i >> 10];
    offs[i] = v;
    cursor[i] = v;
  }
  if (i == 0) offs[n] = e;
}

__global__ void fill_kernel(const int* __restrict__ erow, const int* __restrict__ ecol,
                            const float* __restrict__ ew, int* __restrict__ cursor,
                            int* __restrict__ csr_col, float* __restrict__ csr_w, int e) {
  int i = blockIdx.x * 256 + threadIdx.x;
  if (i < e) {
    int r = erow[i];
    int slot = atomicAdd(&cursor[r], 1);
    csr_col[slot] = ecol[i];
    csr_w[slot] = ew[i];
  }
}

// ---------------------------------------------------------------------------
// SpMM1 + bias + relu + dropout: x2[row,:] = relu(sum_e w*xw[col,:] + b1)*mask
// one wave per row, lane handles 2 feats (float2)
// ---------------------------------------------------------------------------
__global__ __launch_bounds__(256) void spmm1_kernel(const int* __restrict__ offs,
                                                    const int* __restrict__ csr_col,
                                                    const float* __restrict__ csr_w,
                                                    const float* __restrict__ xw,
                                                    const float* __restrict__ b1,
                                                    const float* __restrict__ dmask,
                                                    float* __restrict__ x2, int n) {
  const int lane = threadIdx.x & 63;
  const int wid = threadIdx.x >> 6;
  const int row = blockIdx.x * 4 + wid;
  if (row >= n) return;
  const int s = offs[row], t = offs[row + 1];
  const float2* xw2 = (const float2*)xw;  // row stride 64 float2
  float ax = 0.f, ay = 0.f;
  int j = s;
  for (; j + 1 < t; j += 2) {
    int c0 = csr_col[j], c1 = csr_col[j + 1];
    float w0 = csr_w[j], w1 = csr_w[j + 1];
    float2 v0 = xw2[c0 * 64 + lane];
    float2 v1 = xw2[c1 * 64 + lane];
    ax += w0 * v0.x + w1 * v1.x;
    ay += w0 * v0.y + w1 * v1.y;
  }
  if (j < t) {
    int c = csr_col[j];
    float w = csr_w[j];
    float2 v = xw2[c * 64 + lane];
    ax += w * v.x;
    ay += w * v.y;
  }
  const int f = lane * 2;
  float h0 = fmaxf(ax + b1[f], 0.f) * dmask[row * NHID + f];
  float h1 = fmaxf(ay + b1[f + 1], 0.f) * dmask[row * NHID + f + 1];
  ((float2*)x2)[row * 64 + lane] = make_float2(h0, h1);
}

// ---------------------------------------------------------------------------
// GEMM2: x2w[n,40] = x2[n,128] @ W2[128,40]; wave per row, lanes 0..39
// ---------------------------------------------------------------------------
__global__ __launch_bounds__(256) void gemm2_kernel(const float* __restrict__ x2,
                                                    const float* __restrict__ W2,
                                                    float* __restrict__ x2w, int n) {
  const int lane = threadIdx.x & 63;
  const int wid = threadIdx.x >> 6;
  const int row = blockIdx.x * 4 + wid;
  if (row >= n || lane >= NCLASS) return;
  const float4* xr4 = (const float4*)(x2 + row * NHID);  // 32 float4
  float acc = 0.f;
#pragma unroll 8
  for (int k4 = 0; k4 < NHID / 4; ++k4) {
    float4 a = xr4[k4];
    int k = k4 * 4;
    acc = fmaf(a.x, W2[(k + 0) * NCLASS + lane], acc);
    acc = fmaf(a.y, W2[(k + 1) * NCLASS + lane], acc);
    acc = fmaf(a.z, W2[(k + 2) * NCLASS + lane], acc);
    acc = fmaf(a.w, W2[(k + 3) * NCLASS + lane], acc);
  }
  x2w[row * NCLASS + lane] = acc;
}

// ---------------------------------------------------------------------------
// SpMM2 + bias: x3[row,c] = sum_e w*x2w[col,c] + b2[c]; wave/row, lanes 0..39
// ---------------------------------------------------------------------------
__global__ __launch_bounds__(256) void spmm2_kernel(const int* __restrict__ offs,
                                                    const int* __restrict__ csr_col,
                                                    const float* __restrict__ csr_w,
                                                    const float* __restrict__ x2w,
                                                    const float* __restrict__ b2,
                                                    float* __restrict__ x3, int n) {
  const int lane = threadIdx.x & 63;
  const int wid = threadIdx.x >> 6;
  const int row = blockIdx.x * 4 + wid;
  if (row >= n || lane >= NCLASS) return;
  const int s = offs[row], t = offs[row + 1];
  float acc = 0.f;
  int j = s;
  for (; j + 1 < t; j += 2) {
    int c0 = csr_col[j], c1 = csr_col[j + 1];
    float w0 = csr_w[j], w1 = csr_w[j + 1];
    acc += w0 * x2w[c0 * NCLASS + lane] + w1 * x2w[c1 * NCLASS + lane];
  }
  if (j < t) acc += csr_w[j] * x2w[csr_col[j] * NCLASS + lane];
  x3[row * NCLASS + lane] = acc + b2[lane];
}

// ---------------------------------------------------------------------------
// log_softmax in place over 40 classes; wave per row (all 64 lanes in shfl)
// ---------------------------------------------------------------------------
__global__ __launch_bounds__(256) void logsoftmax_kernel(float* __restrict__ x3, int n) {
  const int lane = threadIdx.x & 63;
  const int wid = threadIdx.x >> 6;
  const int row = blockIdx.x * 4 + wid;
  if (row >= n) return;
  float v = (lane < NCLASS) ? x3[row * NCLASS + lane] : -__builtin_inff();
  float m = v;
#pragma unroll
  for (int off = 32; off > 0; off >>= 1) m = fmaxf(m, __shfl_xor(m, off, 64));
  float ex = (lane < NCLASS) ? expf(v - m) : 0.f;
  float ssum = ex;
#pragma unroll
  for (int off = 32; off > 0; off >>= 1) ssum += __shfl_xor(ssum, off, 64);
  if (lane < NCLASS) x3[row * NCLASS + lane] = v - m - logf(ssum);
}

// ---------------------------------------------------------------------------
extern "C" void kernel_launch(void* const* d_in, const int* in_sizes, int n_in,
                              void* d_out, int out_size, void* d_ws, size_t ws_size,
                              hipStream_t stream) {
  const float* x = (const float*)d_in[0];
  const int* erow = (const int*)d_in[1];
  const int* ecol = (const int*)d_in[2];
  const float* ew = (const float*)d_in[3];
  const float* W1 = (const float*)d_in[4];
  const float* b1 = (const float*)d_in[5];
  const float* W2 = (const float*)d_in[6];
  const float* b2 = (const float*)d_in[7];
  const float* dmask = (const float*)d_in[8];

  const int n = in_sizes[0] / NFEAT;  // 100000
  const int e = in_sizes[1];          // 3200000

  float* out_ls = (float*)d_out;                 // [n,40] log_softmax
  float* x2 = out_ls + (size_t)n * NCLASS;       // [n,128] dropout output

  // workspace layout (floats/ints, 4B each)
  float* ws = (float*)d_ws;
  float* bufA = ws;                               // n*128: xw, then reused for x2w
  size_t off = (size_t)n * NHID;
  int* csr_col = (int*)(ws + off); off += e;
  float* csr_w = ws + off; off += e;
  int* offs = (int*)(ws + off); off += (size_t)n + 1;
  int* cursor = (int*)(ws + off); off += n;
  int* bsum = (int*)(ws + off); off += 512;

  // zero degree counters (ws is poisoned each call)
  hipMemsetAsync(cursor, 0, (size_t)n * sizeof(int), stream);

  // dense layer 1
  gemm1_kernel<<<(n + 63) / 64, 256, 0, stream>>>(x, W1, bufA, n);

  // CSR build
  count_kernel<<<(e + 255) / 256, 256, 0, stream>>>(erow, cursor, e);
  int nblk = (n + 1023) / 1024;
  scanA_kernel<<<nblk, 256, 0, stream>>>(cursor, offs, bsum, n);
  scanB_kernel<<<1, 256, 0, stream>>>(bsum, nblk);
  scanC_kernel<<<(n + 255) / 256, 256, 0, stream>>>(offs, bsum, cursor, n, e);
  fill_kernel<<<(e + 255) / 256, 256, 0, stream>>>(erow, ecol, ew, cursor, csr_col, csr_w, e);

  // SpMM1 + bias + relu + dropout -> x2 (in d_out)
  spmm1_kernel<<<(n + 3) / 4, 256, 0, stream>>>(offs, csr_col, csr_w, bufA, b1, dmask, x2, n);

  // dense layer 2 (bufA reused for x2w)
  gemm2_kernel<<<(n + 3) / 4, 256, 0, stream>>>(x2, W2, bufA, n);

  // SpMM2 + bias -> x3 (in d_out), then log_softmax in place
  spmm2_kernel<<<(n + 3) / 4, 256, 0, stream>>>(offs, csr_col, csr_w, bufA, b2, out_ls, n);
  logsoftmax_kernel<<<(n + 3) / 4, 256, 0, stream>>>(out_ls, n);
}

// Round 2
// 1349.894 us; speedup vs baseline: 1.0314x; 1.0314x over previous
//
#include <hip/hip_runtime.h>
#include <math.h>

#define NFEAT 512
#define NHID  128
#define NCLASS 40

typedef __bf16 bf16x8 __attribute__((ext_vector_type(8)));
typedef __bf16 bf16x2 __attribute__((ext_vector_type(2)));
typedef float f32x4 __attribute__((ext_vector_type(4)));

// ---------------------------------------------------------------------------
// W1 [512,128] f32 -> Bt [128,512] bf16 (transposed, for B-fragment loads)
// ---------------------------------------------------------------------------
__global__ void convW1_kernel(const float* __restrict__ W1, __bf16* __restrict__ Bt) {
  int i = blockIdx.x * 256 + threadIdx.x;  // 65536 total
  int kk = i >> 7, nn = i & 127;
  Bt[nn * 512 + kk] = (__bf16)W1[i];
}

static __device__ inline bf16x8 cvt8(float4 a, float4 b) {
  bf16x8 r;
  r[0] = (__bf16)a.x; r[1] = (__bf16)a.y; r[2] = (__bf16)a.z; r[3] = (__bf16)a.w;
  r[4] = (__bf16)b.x; r[5] = (__bf16)b.y; r[6] = (__bf16)b.z; r[7] = (__bf16)b.w;
  return r;
}

// ---------------------------------------------------------------------------
// GEMM1 (MFMA bf16): xw_bf16[n,128] = bf16(X[n,512] @ W1[512,128])
// block = 4 waves, tile 64 rows x 128 cols; wave w -> rows w*16..w*16+15
// ---------------------------------------------------------------------------
__global__ __launch_bounds__(256) void gemm1_mfma_kernel(const float* __restrict__ X,
                                                         const __bf16* __restrict__ Bt,
                                                         __bf16* __restrict__ xwb, int n) {
  __shared__ __bf16 cs[64][128];  // 16 KB epilogue transpose buffer
  const int tid = threadIdx.x;
  const int lane = tid & 63;
  const int wid = tid >> 6;
  const int m = lane & 15;
  const int quad = lane >> 4;
  const int row0 = blockIdx.x * 64;
  const int grow = row0 + wid * 16 + m;
  const bool rowok = (grow < n);

  const float4* Xr = (const float4*)X + (size_t)(rowok ? grow : 0) * (NFEAT / 4);
  const bf16x8* Btv = (const bf16x8*)Bt;  // [128][512/8]

  f32x4 acc[8];
#pragma unroll
  for (int t = 0; t < 8; ++t) acc[t] = (f32x4){0.f, 0.f, 0.f, 0.f};

  const float4 z4 = make_float4(0.f, 0.f, 0.f, 0.f);
#pragma unroll
  for (int ks = 0; ks < 16; ++ks) {
    const int kq = ks * 4 + quad;  // float4 index of k0+quad*8
    float4 a0 = rowok ? Xr[kq * 2] : z4;
    float4 a1 = rowok ? Xr[kq * 2 + 1] : z4;
    bf16x8 af = cvt8(a0, a1);
#pragma unroll
    for (int t = 0; t < 8; ++t) {
      bf16x8 bfr = Btv[(t * 16 + m) * 64 + kq];
      acc[t] = __builtin_amdgcn_mfma_f32_16x16x32_bf16(af, bfr, acc[t], 0, 0, 0);
    }
  }

  // epilogue: C/D layout col=lane&15, row=quad*4+r  -> LDS -> coalesced bf16 stores
#pragma unroll
  for (int t = 0; t < 8; ++t)
#pragma unroll
    for (int r = 0; r < 4; ++r)
      cs[wid * 16 + quad * 4 + r][t * 16 + m] = (__bf16)acc[t][r];
  __syncthreads();

  const bf16x8* csv = (const bf16x8*)&cs[0][0];
  bf16x8* xwv = (bf16x8*)xwb;
#pragma unroll
  for (int i = 0; i < 4; ++i) {
    int p = tid + i * 256;          // 1024 chunks of 8 bf16
    int r = p >> 4, c8 = p & 15;
    int gr = row0 + r;
    if (gr < n) xwv[(size_t)gr * 16 + c8] = csv[p];
  }
}

// ---------------------------------------------------------------------------
// CSR build: count -> scan -> fill (col+w packed as int2)
// ---------------------------------------------------------------------------
__global__ void count_kernel(const int* __restrict__ erow, int* __restrict__ cnt, int e) {
  int i = blockIdx.x * 256 + threadIdx.x;
  if (i < e) atomicAdd(&cnt[erow[i]], 1);
}

__global__ __launch_bounds__(256) void scanA_kernel(const int* __restrict__ cnt,
                                                    int* __restrict__ part,
                                                    int* __restrict__ bsum, int n) {
  __shared__ int s[256];
  const int tid = threadIdx.x;
  const int base = blockIdx.x * 1024 + tid * 4;
  int v0 = (base + 0 < n) ? cnt[base + 0] : 0;
  int v1 = (base + 1 < n) ? cnt[base + 1] : 0;
  int v2 = (base + 2 < n) ? cnt[base + 2] : 0;
  int v3 = (base + 3 < n) ? cnt[base + 3] : 0;
  int tsum = v0 + v1 + v2 + v3;
  s[tid] = tsum;
  __syncthreads();
  for (int off = 1; off < 256; off <<= 1) {
    int x = (tid >= off) ? s[tid - off] : 0;
    __syncthreads();
    s[tid] += x;
    __syncthreads();
  }
  int excl = s[tid] - tsum;
  if (base + 0 < n) part[base + 0] = excl;
  if (base + 1 < n) part[base + 1] = excl + v0;
  if (base + 2 < n) part[base + 2] = excl + v0 + v1;
  if (base + 3 < n) part[base + 3] = excl + v0 + v1 + v2;
  if (tid == 255) bsum[blockIdx.x] = s[255];
}

__global__ __launch_bounds__(256) void scanB_kernel(int* __restrict__ bsum, int nb) {
  __shared__ int s[256];
  const int tid = threadIdx.x;
  int own = (tid < nb) ? bsum[tid] : 0;
  s[tid] = own;
  __syncthreads();
  for (int off = 1; off < 256; off <<= 1) {
    int x = (tid >= off) ? s[tid - off] : 0;
    __syncthreads();
    s[tid] += x;
    __syncthreads();
  }
  if (tid < nb) bsum[tid] = s[tid] - own;
}

__global__ void scanC_kernel(int* __restrict__ offs, const int* __restrict__ bsum,
                             int* __restrict__ cursor, int n, int e) {
  int i = blockIdx.x * 256 + threadIdx.x;
  if (i < n) {
    int v = offs[i] + bsum[i >> 10];
    offs[i] = v;
    cursor[i] = v;
  }
  if (i == 0) offs[n] = e;
}

__global__ void fill_kernel(const int* __restrict__ erow, const int* __restrict__ ecol,
                            const float* __restrict__ ew, int* __restrict__ cursor,
                            int2* __restrict__ csr, int e) {
  int i = blockIdx.x * 256 + threadIdx.x;
  if (i < e) {
    int r = erow[i];
    int slot = atomicAdd(&cursor[r], 1);
    csr[slot] = make_int2(ecol[i], __float_as_int(ew[i]));
  }
}

// ---------------------------------------------------------------------------
// SpMM1 + bias + relu + dropout (bf16 gathers): x2 = relu(A@xw + b1)*mask
// wave per row; lane handles 2 feats
// ---------------------------------------------------------------------------
__global__ __launch_bounds__(256) void spmm1_kernel(const int* __restrict__ offs,
                                                    const int2* __restrict__ csr,
                                                    const __bf16* __restrict__ xwb,
                                                    const float* __restrict__ b1,
                                                    const float* __restrict__ dmask,
                                                    float* __restrict__ x2, int n) {
  const int lane = threadIdx.x & 63;
  const int wid = threadIdx.x >> 6;
  const int row = blockIdx.x * 4 + wid;
  if (row >= n) return;
  const int s = offs[row], t = offs[row + 1];
  const bf16x2* xw2 = (const bf16x2*)xwb;  // row stride 64 bf16x2
  float ax = 0.f, ay = 0.f;
  int j = s;
  for (; j + 3 < t; j += 4) {
    int2 c0 = csr[j], c1 = csr[j + 1], c2 = csr[j + 2], c3 = csr[j + 3];
    bf16x2 v0 = xw2[(size_t)c0.x * 64 + lane];
    bf16x2 v1 = xw2[(size_t)c1.x * 64 + lane];
    bf16x2 v2 = xw2[(size_t)c2.x * 64 + lane];
    bf16x2 v3 = xw2[(size_t)c3.x * 64 + lane];
    float w0 = __int_as_float(c0.y), w1 = __int_as_float(c1.y);
    float w2 = __int_as_float(c2.y), w3 = __int_as_float(c3.y);
    ax += w0 * (float)v0[0] + w1 * (float)v1[0] + w2 * (float)v2[0] + w3 * (float)v3[0];
    ay += w0 * (float)v0[1] + w1 * (float)v1[1] + w2 * (float)v2[1] + w3 * (float)v3[1];
  }
  for (; j < t; ++j) {
    int2 c = csr[j];
    float w = __int_as_float(c.y);
    bf16x2 v = xw2[(size_t)c.x * 64 + lane];
    ax += w * (float)v[0];
    ay += w * (float)v[1];
  }
  const int f = lane * 2;
  float2 dm = ((const float2*)dmask)[row * 64 + lane];
  float h0 = fmaxf(ax + b1[f], 0.f) * dm.x;
  float h1 = fmaxf(ay + b1[f + 1], 0.f) * dm.y;
  ((float2*)x2)[row * 64 + lane] = make_float2(h0, h1);
}

// ---------------------------------------------------------------------------
// GEMM2: x2w_bf16[n,40] = bf16(x2[n,128] @ W2[128,40]); wave/row, lanes 0..39
// ---------------------------------------------------------------------------
__global__ __launch_bounds__(256) void gemm2_kernel(const float* __restrict__ x2,
                                                    const float* __restrict__ W2,
                                                    __bf16* __restrict__ x2wb, int n) {
  const int lane = threadIdx.x & 63;
  const int wid = threadIdx.x >> 6;
  const int row = blockIdx.x * 4 + wid;
  if (row >= n || lane >= NCLASS) return;
  const float4* xr4 = (const float4*)(x2 + (size_t)row * NHID);
  float acc = 0.f;
#pragma unroll 8
  for (int k4 = 0; k4 < NHID / 4; ++k4) {
    float4 a = xr4[k4];
    int k = k4 * 4;
    acc = fmaf(a.x, W2[(k + 0) * NCLASS + lane], acc);
    acc = fmaf(a.y, W2[(k + 1) * NCLASS + lane], acc);
    acc = fmaf(a.z, W2[(k + 2) * NCLASS + lane], acc);
    acc = fmaf(a.w, W2[(k + 3) * NCLASS + lane], acc);
  }
  x2wb[(size_t)row * NCLASS + lane] = (__bf16)acc;
}

// ---------------------------------------------------------------------------
// SpMM2 + bias (bf16 gathers): x3[row,c] = sum w*x2w[col,c] + b2[c]
// ---------------------------------------------------------------------------
__global__ __launch_bounds__(256) void spmm2_kernel(const int* __restrict__ offs,
                                                    const int2* __restrict__ csr,
                                                    const __bf16* __restrict__ x2wb,
                                                    const float* __restrict__ b2,
                                                    float* __restrict__ x3, int n) {
  const int lane = threadIdx.x & 63;
  const int wid = threadIdx.x >> 6;
  const int row = blockIdx.x * 4 + wid;
  if (row >= n || lane >= NCLASS) return;
  const int s = offs[row], t = offs[row + 1];
  float acc = 0.f;
  int j = s;
  for (; j + 3 < t; j += 4) {
    int2 c0 = csr[j], c1 = csr[j + 1], c2 = csr[j + 2], c3 = csr[j + 3];
    float g0 = (float)x2wb[(size_t)c0.x * NCLASS + lane];
    float g1 = (float)x2wb[(size_t)c1.x * NCLASS + lane];
    float g2 = (float)x2wb[(size_t)c2.x * NCLASS + lane];
    float g3 = (float)x2wb[(size_t)c3.x * NCLASS + lane];
    acc += __int_as_float(c0.y) * g0 + __int_as_float(c1.y) * g1 +
           __int_as_float(c2.y) * g2 + __int_as_float(c3.y) * g3;
  }
  for (; j < t; ++j) {
    int2 c = csr[j];
    acc += __int_as_float(c.y) * (float)x2wb[(size_t)c.x * NCLASS + lane];
  }
  x3[(size_t)row * NCLASS + lane] = acc + b2[lane];
}

// ---------------------------------------------------------------------------
// log_softmax in place over 40 classes; wave per row
// ---------------------------------------------------------------------------
__global__ __launch_bounds__(256) void logsoftmax_kernel(float* __restrict__ x3, int n) {
  const int lane = threadIdx.x & 63;
  const int wid = threadIdx.x >> 6;
  const int row = blockIdx.x * 4 + wid;
  if (row >= n) return;
  float v = (lane < NCLASS) ? x3[(size_t)row * NCLASS + lane] : -__builtin_inff();
  float m = v;
#pragma unroll
  for (int off = 32; off > 0; off >>= 1) m = fmaxf(m, __shfl_xor(m, off, 64));
  float ex = (lane < NCLASS) ? expf(v - m) : 0.f;
  float ssum = ex;
#pragma unroll
  for (int off = 32; off > 0; off >>= 1) ssum += __shfl_xor(ssum, off, 64);
  if (lane < NCLASS) x3[(size_t)row * NCLASS + lane] = v - m - logf(ssum);
}

// ---------------------------------------------------------------------------
extern "C" void kernel_launch(void* const* d_in, const int* in_sizes, int n_in,
                              void* d_out, int out_size, void* d_ws, size_t ws_size,
                              hipStream_t stream) {
  const float* x = (const float*)d_in[0];
  const int* erow = (const int*)d_in[1];
  const int* ecol = (const int*)d_in[2];
  const float* ew = (const float*)d_in[3];
  const float* W1 = (const float*)d_in[4];
  // const float* b1p = (const float*)d_in[5];
  const float* W2 = (const float*)d_in[6];
  const float* b2 = (const float*)d_in[7];
  const float* dmask = (const float*)d_in[8];
  const float* b1 = (const float*)d_in[5];

  const int n = in_sizes[0] / NFEAT;  // 100000
  const int e = in_sizes[1];          // 3200000

  float* out_ls = (float*)d_out;             // [n,40]
  float* x2 = out_ls + (size_t)n * NCLASS;   // [n,128]

  // workspace layout (16B-aligned segments)
  uintptr_t p = (uintptr_t)d_ws;
  __bf16* xwb = (__bf16*)p;  p += (size_t)n * NHID * 2;     // 25.6 MB
  __bf16* Btb = (__bf16*)p;  p += (size_t)NHID * NFEAT * 2; // 128 KB
  __bf16* x2wb = (__bf16*)p; p += (size_t)n * NCLASS * 2;   // 8 MB
  int2* csr = (int2*)p;      p += (size_t)e * 8;            // 25.6 MB
  int* offs = (int*)p;       p += ((size_t)n + 1) * 4;
  int* cursor = (int*)p;     p += (size_t)n * 4;
  int* bsum = (int*)p;       p += 512 * 4;

  hipMemsetAsync(cursor, 0, (size_t)n * sizeof(int), stream);

  convW1_kernel<<<NFEAT * NHID / 256, 256, 0, stream>>>(W1, Btb);
  gemm1_mfma_kernel<<<(n + 63) / 64, 256, 0, stream>>>(x, Btb, xwb, n);

  count_kernel<<<(e + 255) / 256, 256, 0, stream>>>(erow, cursor, e);
  int nblk = (n + 1023) / 1024;
  scanA_kernel<<<nblk, 256, 0, stream>>>(cursor, offs, bsum, n);
  scanB_kernel<<<1, 256, 0, stream>>>(bsum, nblk);
  scanC_kernel<<<(n + 255) / 256, 256, 0, stream>>>(offs, bsum, cursor, n, e);
  fill_kernel<<<(e + 255) / 256, 256, 0, stream>>>(erow, ecol, ew, cursor, csr, e);

  spmm1_kernel<<<(n + 3) / 4, 256, 0, stream>>>(offs, csr, xwb, b1, dmask, x2, n);
  gemm2_kernel<<<(n + 3) / 4, 256, 0, stream>>>(x2, W2, x2wb, n);
  spmm2_kernel<<<(n + 3) / 4, 256, 0, stream>>>(offs, csr, x2wb, b2, out_ls, n);
  logsoftmax_kernel<<<(n + 3) / 4, 256, 0, stream>>>(out_ls, n);
}

// Round 3
// 1249.672 us; speedup vs baseline: 1.1141x; 1.0802x over previous
//
#include <hip/hip_runtime.h>
#include <math.h>

#define NFEAT 512
#define NHID  128
#define NCLASS 40

typedef __bf16 bf16x8 __attribute__((ext_vector_type(8)));
typedef __bf16 bf16x4 __attribute__((ext_vector_type(4)));
typedef __bf16 bf16x2 __attribute__((ext_vector_type(2)));
typedef float f32x4 __attribute__((ext_vector_type(4)));

// ---------------------------------------------------------------------------
// W1 [512,128] f32 -> Bt [128,512] bf16 (transposed)
// ---------------------------------------------------------------------------
__global__ void convW1_kernel(const float* __restrict__ W1, __bf16* __restrict__ Bt) {
  int i = blockIdx.x * 256 + threadIdx.x;  // 65536
  int kk = i >> 7, nn = i & 127;
  Bt[nn * 512 + kk] = (__bf16)W1[i];
}

// ---------------------------------------------------------------------------
// GEMM1 (tiled MFMA bf16): xwb[n,128] = bf16(X[n,512] @ W1)
// block=256 (4 waves), tile 64 rows x 128 cols, BK=32, register prefetch.
// LDS strides padded to 48 bf16 (96B): 16B-aligned b128 frags, uniform banks.
// ---------------------------------------------------------------------------
#define ASTR 48
#define BSTR 48
__global__ __launch_bounds__(256) void gemm1_mfma_kernel(const float* __restrict__ X,
                                                         const __bf16* __restrict__ Bt,
                                                         __bf16* __restrict__ xwb, int n) {
  __shared__ __bf16 smem[64 * ASTR + 128 * BSTR];  // 18432 B; epilogue reuses it
  __bf16* As = smem;              // [64][48]
  __bf16* Bs = smem + 64 * ASTR;  // [128][48]

  const int tid = threadIdx.x;
  const int lane = tid & 63;
  const int wid = tid >> 6;
  const int m = lane & 15;
  const int quad = lane >> 4;
  const int row0 = blockIdx.x * 64;

  f32x4 acc[8];
#pragma unroll
  for (int t = 0; t < 8; ++t) acc[t] = (f32x4){0.f, 0.f, 0.f, 0.f};

  // staging assignments
  const int ar = tid >> 3, aq = tid & 7;   // A: rows ar, ar+32; float4 col aq (of 8)
  const int bc = tid >> 2, bq = tid & 3;   // B: cols bc, bc+64; 16B chunk bq (of 4)

  const float4* X4 = (const float4*)X;       // row stride 128 float4
  const bf16x8* Bt8 = (const bf16x8*)Bt;     // row stride 64 chunks
  const float4 z4 = make_float4(0.f, 0.f, 0.f, 0.f);
  const int r1 = row0 + ar, r2 = row0 + 32 + ar;
  const bool ok1 = r1 < n, ok2 = r2 < n;

  float4 a0, a1;
  bf16x8 b0, b1;
  // prefetch kt=0
  a0 = ok1 ? X4[(size_t)r1 * 128 + aq] : z4;
  a1 = ok2 ? X4[(size_t)r2 * 128 + aq] : z4;
  b0 = Bt8[(size_t)bc * 64 + bq];
  b1 = Bt8[(size_t)(64 + bc) * 64 + bq];

  for (int kt = 0; kt < 16; ++kt) {
    __syncthreads();  // previous iter's frag reads done
    // store staged regs to LDS (cvt f32->bf16 for A)
    bf16x4 av0, av1;
    av0[0] = (__bf16)a0.x; av0[1] = (__bf16)a0.y; av0[2] = (__bf16)a0.z; av0[3] = (__bf16)a0.w;
    av1[0] = (__bf16)a1.x; av1[1] = (__bf16)a1.y; av1[2] = (__bf16)a1.z; av1[3] = (__bf16)a1.w;
    *(bf16x4*)&As[ar * ASTR + aq * 4] = av0;
    *(bf16x4*)&As[(32 + ar) * ASTR + aq * 4] = av1;
    *(bf16x8*)&Bs[bc * BSTR + bq * 8] = b0;
    *(bf16x8*)&Bs[(64 + bc) * BSTR + bq * 8] = b1;
    __syncthreads();
    if (kt < 15) {  // prefetch next tile while computing
      int ko = (kt + 1) * 8, kc = (kt + 1) * 4;
      a0 = ok1 ? X4[(size_t)r1 * 128 + ko + aq] : z4;
      a1 = ok2 ? X4[(size_t)r2 * 128 + ko + aq] : z4;
      b0 = Bt8[(size_t)bc * 64 + kc + bq];
      b1 = Bt8[(size_t)(64 + bc) * 64 + kc + bq];
    }
    bf16x8 af = *(const bf16x8*)&As[(wid * 16 + m) * ASTR + quad * 8];
#pragma unroll
    for (int t = 0; t < 8; ++t) {
      bf16x8 bfr = *(const bf16x8*)&Bs[(t * 16 + m) * BSTR + quad * 8];
      acc[t] = __builtin_amdgcn_mfma_f32_16x16x32_bf16(af, bfr, acc[t], 0, 0, 0);
    }
  }

  // epilogue: C/D layout col=lane&15, row=quad*4+r -> LDS -> coalesced stores
  __syncthreads();
  __bf16* cs = smem;  // [64][136]
#pragma unroll
  for (int t = 0; t < 8; ++t)
#pragma unroll
    for (int r = 0; r < 4; ++r)
      cs[(wid * 16 + quad * 4 + r) * 136 + t * 16 + m] = (__bf16)acc[t][r];
  __syncthreads();
  bf16x8* xwv = (bf16x8*)xwb;
#pragma unroll
  for (int i = 0; i < 4; ++i) {
    int p = tid + i * 256;          // 1024 chunks of 8 bf16
    int r = p >> 4, c8 = p & 15;
    int gr = row0 + r;
    if (gr < n) xwv[(size_t)gr * 16 + c8] = *(const bf16x8*)&cs[r * 136 + c8 * 8];
  }
}

// ---------------------------------------------------------------------------
// CSR build: count -> scan -> bucket-partition -> in-bucket scatter
// ---------------------------------------------------------------------------
__global__ void count_kernel(const int* __restrict__ erow, int* __restrict__ cnt, int e) {
  int i = blockIdx.x * 256 + threadIdx.x;
  if (i < e) atomicAdd(&cnt[erow[i]], 1);
}

__global__ __launch_bounds__(256) void scanA_kernel(const int* __restrict__ cnt,
                                                    int* __restrict__ part,
                                                    int* __restrict__ bsum, int n) {
  __shared__ int s[256];
  const int tid = threadIdx.x;
  const int base = blockIdx.x * 1024 + tid * 4;
  int v0 = (base + 0 < n) ? cnt[base + 0] : 0;
  int v1 = (base + 1 < n) ? cnt[base + 1] : 0;
  int v2 = (base + 2 < n) ? cnt[base + 2] : 0;
  int v3 = (base + 3 < n) ? cnt[base + 3] : 0;
  int tsum = v0 + v1 + v2 + v3;
  s[tid] = tsum;
  __syncthreads();
  for (int off = 1; off < 256; off <<= 1) {
    int x = (tid >= off) ? s[tid - off] : 0;
    __syncthreads();
    s[tid] += x;
    __syncthreads();
  }
  int excl = s[tid] - tsum;
  if (base + 0 < n) part[base + 0] = excl;
  if (base + 1 < n) part[base + 1] = excl + v0;
  if (base + 2 < n) part[base + 2] = excl + v0 + v1;
  if (base + 3 < n) part[base + 3] = excl + v0 + v1 + v2;
  if (tid == 255) bsum[blockIdx.x] = s[255];
}

__global__ __launch_bounds__(256) void scanB_kernel(int* __restrict__ bsum, int nb) {
  __shared__ int s[256];
  const int tid = threadIdx.x;
  int own = (tid < nb) ? bsum[tid] : 0;
  s[tid] = own;
  __syncthreads();
  for (int off = 1; off < 256; off <<= 1) {
    int x = (tid >= off) ? s[tid - off] : 0;
    __syncthreads();
    s[tid] += x;
    __syncthreads();
  }
  if (tid < nb) bsum[tid] = s[tid] - own;
}

// offs[i] final; also emit bucket cursors bcur[b] = offs[32b]
__global__ void scanC_kernel(int* __restrict__ offs, const int* __restrict__ bsum,
                             int* __restrict__ bcur, int n, int e) {
  int i = blockIdx.x * 256 + threadIdx.x;
  if (i < n) {
    int v = offs[i] + bsum[i >> 10];
    offs[i] = v;
    if ((i & 31) == 0) bcur[i >> 5] = v;
  }
  if (i == 0) offs[n] = e;
}

// pass 2: partition edges into 32-row buckets; payload packs rel-row in bits 17..21
__global__ void partition_kernel(const int* __restrict__ erow, const int* __restrict__ ecol,
                                 const float* __restrict__ ew, int* __restrict__ bcur,
                                 int2* __restrict__ tmp, int e) {
  int i = blockIdx.x * 256 + threadIdx.x;
  if (i < e) {
    int r = erow[i];
    int slot = atomicAdd(&bcur[r >> 5], 1);
    tmp[slot] = make_int2(ecol[i] | ((r & 31) << 17), __float_as_int(ew[i]));
  }
}

// pass 3: block per bucket; LDS row cursors; scatter within L2-resident span
__global__ __launch_bounds__(256) void scatter_kernel(const int* __restrict__ offs,
                                                      const int2* __restrict__ tmp,
                                                      int2* __restrict__ csr, int n) {
  __shared__ int lcur[32];
  const int b = blockIdx.x;
  const int r0 = b << 5;
  const int tid = threadIdx.x;
  if (tid < 32) {
    int rr = r0 + tid;
    lcur[tid] = offs[rr < n ? rr : n];
  }
  int s = offs[r0];
  int rend = r0 + 32;
  int t = offs[rend < n ? rend : n];
  __syncthreads();
  for (int i = s + tid; i < t; i += 256) {
    int2 eu = tmp[i];
    int rel = (eu.x >> 17) & 31;
    int col = eu.x & 0x1FFFF;
    int slot = atomicAdd(&lcur[rel], 1);
    csr[slot] = make_int2(col, eu.y);
  }
}

// ---------------------------------------------------------------------------
// SpMM1 + bias + relu + dropout (bf16 gathers)
// ---------------------------------------------------------------------------
__global__ __launch_bounds__(256) void spmm1_kernel(const int* __restrict__ offs,
                                                    const int2* __restrict__ csr,
                                                    const __bf16* __restrict__ xwb,
                                                    const float* __restrict__ b1,
                                                    const float* __restrict__ dmask,
                                                    float* __restrict__ x2, int n) {
  const int lane = threadIdx.x & 63;
  const int wid = threadIdx.x >> 6;
  const int row = blockIdx.x * 4 + wid;
  if (row >= n) return;
  const int s = offs[row], t = offs[row + 1];
  const bf16x2* xw2 = (const bf16x2*)xwb;  // row stride 64
  float ax = 0.f, ay = 0.f;
  int j = s;
  for (; j + 3 < t; j += 4) {
    int2 c0 = csr[j], c1 = csr[j + 1], c2 = csr[j + 2], c3 = csr[j + 3];
    bf16x2 v0 = xw2[(size_t)c0.x * 64 + lane];
    bf16x2 v1 = xw2[(size_t)c1.x * 64 + lane];
    bf16x2 v2 = xw2[(size_t)c2.x * 64 + lane];
    bf16x2 v3 = xw2[(size_t)c3.x * 64 + lane];
    float w0 = __int_as_float(c0.y), w1 = __int_as_float(c1.y);
    float w2 = __int_as_float(c2.y), w3 = __int_as_float(c3.y);
    ax += w0 * (float)v0[0] + w1 * (float)v1[0] + w2 * (float)v2[0] + w3 * (float)v3[0];
    ay += w0 * (float)v0[1] + w1 * (float)v1[1] + w2 * (float)v2[1] + w3 * (float)v3[1];
  }
  for (; j < t; ++j) {
    int2 c = csr[j];
    float w = __int_as_float(c.y);
    bf16x2 v = xw2[(size_t)c.x * 64 + lane];
    ax += w * (float)v[0];
    ay += w * (float)v[1];
  }
  const int f = lane * 2;
  float2 dm = ((const float2*)dmask)[row * 64 + lane];
  float h0 = fmaxf(ax + b1[f], 0.f) * dm.x;
  float h1 = fmaxf(ay + b1[f + 1], 0.f) * dm.y;
  ((float2*)x2)[row * 64 + lane] = make_float2(h0, h1);
}

// ---------------------------------------------------------------------------
// GEMM2: x2wb[n,40] = bf16(x2[n,128] @ W2[128,40])
// ---------------------------------------------------------------------------
__global__ __launch_bounds__(256) void gemm2_kernel(const float* __restrict__ x2,
                                                    const float* __restrict__ W2,
                                                    __bf16* __restrict__ x2wb, int n) {
  const int lane = threadIdx.x & 63;
  const int wid = threadIdx.x >> 6;
  const int row = blockIdx.x * 4 + wid;
  if (row >= n || lane >= NCLASS) return;
  const float4* xr4 = (const float4*)(x2 + (size_t)row * NHID);
  float acc = 0.f;
#pragma unroll 8
  for (int k4 = 0; k4 < NHID / 4; ++k4) {
    float4 a = xr4[k4];
    int k = k4 * 4;
    acc = fmaf(a.x, W2[(k + 0) * NCLASS + lane], acc);
    acc = fmaf(a.y, W2[(k + 1) * NCLASS + lane], acc);
    acc = fmaf(a.z, W2[(k + 2) * NCLASS + lane], acc);
    acc = fmaf(a.w, W2[(k + 3) * NCLASS + lane], acc);
  }
  x2wb[(size_t)row * NCLASS + lane] = (__bf16)acc;
}

// ---------------------------------------------------------------------------
// SpMM2 + bias (bf16 gathers)
// ---------------------------------------------------------------------------
__global__ __launch_bounds__(256) void spmm2_kernel(const int* __restrict__ offs,
                                                    const int2* __restrict__ csr,
                                                    const __bf16* __restrict__ x2wb,
                                                    const float* __restrict__ b2,
                                                    float* __restrict__ x3, int n) {
  const int lane = threadIdx.x & 63;
  const int wid = threadIdx.x >> 6;
  const int row = blockIdx.x * 4 + wid;
  if (row >= n || lane >= NCLASS) return;
  const int s = offs[row], t = offs[row + 1];
  float acc = 0.f;
  int j = s;
  for (; j + 3 < t; j += 4) {
    int2 c0 = csr[j], c1 = csr[j + 1], c2 = csr[j + 2], c3 = csr[j + 3];
    float g0 = (float)x2wb[(size_t)c0.x * NCLASS + lane];
    float g1 = (float)x2wb[(size_t)c1.x * NCLASS + lane];
    float g2 = (float)x2wb[(size_t)c2.x * NCLASS + lane];
    float g3 = (float)x2wb[(size_t)c3.x * NCLASS + lane];
    acc += __int_as_float(c0.y) * g0 + __int_as_float(c1.y) * g1 +
           __int_as_float(c2.y) * g2 + __int_as_float(c3.y) * g3;
  }
  for (; j < t; ++j) {
    int2 c = csr[j];
    acc += __int_as_float(c.y) * (float)x2wb[(size_t)c.x * NCLASS + lane];
  }
  x3[(size_t)row * NCLASS + lane] = acc + b2[lane];
}

// ---------------------------------------------------------------------------
// log_softmax in place over 40 classes
// ---------------------------------------------------------------------------
__global__ __launch_bounds__(256) void logsoftmax_kernel(float* __restrict__ x3, int n) {
  const int lane = threadIdx.x & 63;
  const int wid = threadIdx.x >> 6;
  const int row = blockIdx.x * 4 + wid;
  if (row >= n) return;
  float v = (lane < NCLASS) ? x3[(size_t)row * NCLASS + lane] : -__builtin_inff();
  float m = v;
#pragma unroll
  for (int off = 32; off > 0; off >>= 1) m = fmaxf(m, __shfl_xor(m, off, 64));
  float ex = (lane < NCLASS) ? expf(v - m) : 0.f;
  float ssum = ex;
#pragma unroll
  for (int off = 32; off > 0; off >>= 1) ssum += __shfl_xor(ssum, off, 64);
  if (lane < NCLASS) x3[(size_t)row * NCLASS + lane] = v - m - logf(ssum);
}

// ---------------------------------------------------------------------------
extern "C" void kernel_launch(void* const* d_in, const int* in_sizes, int n_in,
                              void* d_out, int out_size, void* d_ws, size_t ws_size,
                              hipStream_t stream) {
  const float* x = (const float*)d_in[0];
  const int* erow = (const int*)d_in[1];
  const int* ecol = (const int*)d_in[2];
  const float* ew = (const float*)d_in[3];
  const float* W1 = (const float*)d_in[4];
  const float* b1 = (const float*)d_in[5];
  const float* W2 = (const float*)d_in[6];
  const float* b2 = (const float*)d_in[7];
  const float* dmask = (const float*)d_in[8];

  const int n = in_sizes[0] / NFEAT;  // 100000
  const int e = in_sizes[1];          // 3200000
  const int nb = (n + 31) >> 5;       // buckets of 32 rows

  float* out_ls = (float*)d_out;             // [n,40]
  float* x2 = out_ls + (size_t)n * NCLASS;   // [n,128]

  // workspace layout (tmp aliases x2wb: tmp dead before gemm2 writes x2wb)
  uintptr_t p = (uintptr_t)d_ws;
  __bf16* xwb = (__bf16*)p;  p += (size_t)n * NHID * 2;      // 25.6 MB
  __bf16* Btb = (__bf16*)p;  p += (size_t)NHID * NFEAT * 2;  // 128 KB
  int2* csr = (int2*)p;      p += (size_t)e * 8;             // 25.6 MB
  int2* tmp = (int2*)p;      __bf16* x2wb = (__bf16*)p;
  p += (size_t)e * 8;                                        // 25.6 MB (shared)
  int* offs = (int*)p;       p += ((size_t)n + 1) * 4;
  int* cnt = (int*)p;        p += (size_t)n * 4;
  int* bcur = (int*)p;       p += (size_t)nb * 4;
  int* bsum = (int*)p;       p += 512 * 4;

  hipMemsetAsync(cnt, 0, (size_t)n * sizeof(int), stream);

  convW1_kernel<<<NFEAT * NHID / 256, 256, 0, stream>>>(W1, Btb);
  gemm1_mfma_kernel<<<(n + 63) / 64, 256, 0, stream>>>(x, Btb, xwb, n);

  count_kernel<<<(e + 255) / 256, 256, 0, stream>>>(erow, cnt, e);
  int nblk = (n + 1023) / 1024;
  scanA_kernel<<<nblk, 256, 0, stream>>>(cnt, offs, bsum, n);
  scanB_kernel<<<1, 256, 0, stream>>>(bsum, nblk);
  scanC_kernel<<<(n + 255) / 256, 256, 0, stream>>>(offs, bsum, bcur, n, e);
  partition_kernel<<<(e + 255) / 256, 256, 0, stream>>>(erow, ecol, ew, bcur, tmp, e);
  scatter_kernel<<<nb, 256, 0, stream>>>(offs, tmp, csr, n);

  spmm1_kernel<<<(n + 3) / 4, 256, 0, stream>>>(offs, csr, xwb, b1, dmask, x2, n);
  gemm2_kernel<<<(n + 3) / 4, 256, 0, stream>>>(x2, W2, x2wb, n);
  spmm2_kernel<<<(n + 3) / 4, 256, 0, stream>>>(offs, csr, x2wb, b2, out_ls, n);
  logsoftmax_kernel<<<(n + 3) / 4, 256, 0, stream>>>(out_ls, n);
}

// Round 4
// 961.381 us; speedup vs baseline: 1.4481x; 1.2999x over previous
//
#include <hip/hip_runtime.h>
#include <math.h>

#define NFEAT 512
#define NHID  128
#define NCLASS 40

// coarse bucket = 512 rows (shift 9); col packed in bits 0..16, rel-row in 17..25
#define BSH 9
#define BROWS 512
#define COLMASK 0x1FFFF
#define PCHUNK 8192

typedef __bf16 bf16x8 __attribute__((ext_vector_type(8)));
typedef __bf16 bf16x4 __attribute__((ext_vector_type(4)));
typedef __bf16 bf16x2 __attribute__((ext_vector_type(2)));
typedef float f32x4 __attribute__((ext_vector_type(4)));

// ---------------------------------------------------------------------------
// W1 [512,128] f32 -> Bt [128,512] bf16 (transposed)
// ---------------------------------------------------------------------------
__global__ void convW1_kernel(const float* __restrict__ W1, __bf16* __restrict__ Bt) {
  int i = blockIdx.x * 256 + threadIdx.x;  // 65536
  int kk = i >> 7, nn = i & 127;
  Bt[nn * 512 + kk] = (__bf16)W1[i];
}

// ---------------------------------------------------------------------------
// GEMM1 (tiled MFMA bf16): xwb[n,128] = bf16(X[n,512] @ W1)
// ---------------------------------------------------------------------------
#define ASTR 48
#define BSTR 48
__global__ __launch_bounds__(256) void gemm1_mfma_kernel(const float* __restrict__ X,
                                                         const __bf16* __restrict__ Bt,
                                                         __bf16* __restrict__ xwb, int n) {
  __shared__ __bf16 smem[64 * ASTR + 128 * BSTR];
  __bf16* As = smem;
  __bf16* Bs = smem + 64 * ASTR;

  const int tid = threadIdx.x;
  const int lane = tid & 63;
  const int wid = tid >> 6;
  const int m = lane & 15;
  const int quad = lane >> 4;
  const int row0 = blockIdx.x * 64;

  f32x4 acc[8];
#pragma unroll
  for (int t = 0; t < 8; ++t) acc[t] = (f32x4){0.f, 0.f, 0.f, 0.f};

  const int ar = tid >> 3, aq = tid & 7;
  const int bc = tid >> 2, bq = tid & 3;

  const float4* X4 = (const float4*)X;
  const bf16x8* Bt8 = (const bf16x8*)Bt;
  const float4 z4 = make_float4(0.f, 0.f, 0.f, 0.f);
  const int r1 = row0 + ar, r2 = row0 + 32 + ar;
  const bool ok1 = r1 < n, ok2 = r2 < n;

  float4 a0, a1;
  bf16x8 b0, b1;
  a0 = ok1 ? X4[(size_t)r1 * 128 + aq] : z4;
  a1 = ok2 ? X4[(size_t)r2 * 128 + aq] : z4;
  b0 = Bt8[(size_t)bc * 64 + bq];
  b1 = Bt8[(size_t)(64 + bc) * 64 + bq];

  for (int kt = 0; kt < 16; ++kt) {
    __syncthreads();
    bf16x4 av0, av1;
    av0[0] = (__bf16)a0.x; av0[1] = (__bf16)a0.y; av0[2] = (__bf16)a0.z; av0[3] = (__bf16)a0.w;
    av1[0] = (__bf16)a1.x; av1[1] = (__bf16)a1.y; av1[2] = (__bf16)a1.z; av1[3] = (__bf16)a1.w;
    *(bf16x4*)&As[ar * ASTR + aq * 4] = av0;
    *(bf16x4*)&As[(32 + ar) * ASTR + aq * 4] = av1;
    *(bf16x8*)&Bs[bc * BSTR + bq * 8] = b0;
    *(bf16x8*)&Bs[(64 + bc) * BSTR + bq * 8] = b1;
    __syncthreads();
    if (kt < 15) {
      int ko = (kt + 1) * 8, kc = (kt + 1) * 4;
      a0 = ok1 ? X4[(size_t)r1 * 128 + ko + aq] : z4;
      a1 = ok2 ? X4[(size_t)r2 * 128 + ko + aq] : z4;
      b0 = Bt8[(size_t)bc * 64 + kc + bq];
      b1 = Bt8[(size_t)(64 + bc) * 64 + kc + bq];
    }
    bf16x8 af = *(const bf16x8*)&As[(wid * 16 + m) * ASTR + quad * 8];
#pragma unroll
    for (int t = 0; t < 8; ++t) {
      bf16x8 bfr = *(const bf16x8*)&Bs[(t * 16 + m) * BSTR + quad * 8];
      acc[t] = __builtin_amdgcn_mfma_f32_16x16x32_bf16(af, bfr, acc[t], 0, 0, 0);
    }
  }

  __syncthreads();
  __bf16* cs = smem;  // [64][136]
#pragma unroll
  for (int t = 0; t < 8; ++t)
#pragma unroll
    for (int r = 0; r < 4; ++r)
      cs[(wid * 16 + quad * 4 + r) * 136 + t * 16 + m] = (__bf16)acc[t][r];
  __syncthreads();
  bf16x8* xwv = (bf16x8*)xwb;
#pragma unroll
  for (int i = 0; i < 4; ++i) {
    int p = tid + i * 256;
    int r = p >> 4, c8 = p & 15;
    int gr = row0 + r;
    if (gr < n) xwv[(size_t)gr * 16 + c8] = *(const bf16x8*)&cs[r * 136 + c8 * 8];
  }
}

// ---------------------------------------------------------------------------
// CSR build pass 0: coarse-bucket histogram (LDS-aggregated)
// ---------------------------------------------------------------------------
__global__ __launch_bounds__(256) void hist_kernel(const int* __restrict__ erow,
                                                   int* __restrict__ bhist, int e, int nb2) {
  __shared__ int h[256];
  const int tid = threadIdx.x;
  h[tid] = 0;
  __syncthreads();
  for (int i = blockIdx.x * 256 + tid; i < e; i += gridDim.x * 256)
    atomicAdd(&h[erow[i] >> BSH], 1);
  __syncthreads();
  if (tid < nb2 && h[tid]) atomicAdd(&bhist[tid], h[tid]);
}

// ---------------------------------------------------------------------------
// pass 1: scan bucket totals -> bbase (exclusive, +sentinel), bcur; offs[n]=e
// single block, nb2 <= 256
// ---------------------------------------------------------------------------
__global__ __launch_bounds__(256) void bucketscan_kernel(const int* __restrict__ bhist,
                                                         int* __restrict__ bbase,
                                                         int* __restrict__ bcur,
                                                         int* __restrict__ offs,
                                                         int n, int e, int nb2) {
  __shared__ int s[256];
  const int tid = threadIdx.x;
  int v = (tid < nb2) ? bhist[tid] : 0;
  s[tid] = v;
  __syncthreads();
  for (int off = 1; off < 256; off <<= 1) {
    int x = (tid >= off) ? s[tid - off] : 0;
    __syncthreads();
    s[tid] += x;
    __syncthreads();
  }
  int excl = s[tid] - v;
  if (tid <= nb2) bbase[tid] = excl;  // bbase[nb2] == e (sentinel)
  if (tid < nb2) bcur[tid] = excl;
  if (tid == 0) offs[n] = e;
}

// ---------------------------------------------------------------------------
// pass 2: chunked counting-sort partition into coarse buckets (grouped writes)
// ---------------------------------------------------------------------------
__global__ __launch_bounds__(256) void partition_kernel(const int* __restrict__ erow,
                                                        const int* __restrict__ ecol,
                                                        const float* __restrict__ ew,
                                                        int* __restrict__ bcur,
                                                        int2* __restrict__ tmp, int e, int nb2) {
  __shared__ int hist[256];
  __shared__ int base[256];
  const int tid = threadIdx.x;
  const int b0 = blockIdx.x * PCHUNK;
  hist[tid] = 0;
  int pk[32], meta[32];
  __syncthreads();
#pragma unroll
  for (int i = 0; i < 32; ++i) {
    int idx = b0 + i * 256 + tid;
    if (idx < e) {
      int r = erow[idx];
      int c = ecol[idx];
      int bk = r >> BSH;
      int rk = atomicAdd(&hist[bk], 1);
      pk[i] = c | ((r & (BROWS - 1)) << 17);
      meta[i] = bk | (rk << 8);
    } else {
      meta[i] = -1;
    }
  }
  __syncthreads();
  if (tid < nb2 && hist[tid]) base[tid] = atomicAdd(&bcur[tid], hist[tid]);
  __syncthreads();
#pragma unroll
  for (int i = 0; i < 32; ++i) {
    if (meta[i] >= 0) {
      int bk = meta[i] & 255, rk = meta[i] >> 8;
      int idx = b0 + i * 256 + tid;
      tmp[base[bk] + rk] = make_int2(pk[i], __float_as_int(ew[idx]));
    }
  }
}

// ---------------------------------------------------------------------------
// pass 3: one block per coarse bucket; per-row LDS counts -> scan -> offs,
// then in-bucket scatter to final CSR (L2-resident span)
// ---------------------------------------------------------------------------
__global__ __launch_bounds__(256) void scatter_kernel(const int* __restrict__ bbase,
                                                      const int2* __restrict__ tmp,
                                                      int2* __restrict__ csr,
                                                      int* __restrict__ offs, int n) {
  __shared__ int rowcnt[BROWS];
  __shared__ int rowptr[BROWS];
  __shared__ int s[256];
  const int b = blockIdx.x, tid = threadIdx.x;
  const int row0 = b << BSH;
  const int s0 = bbase[b], s1 = bbase[b + 1];
  rowcnt[tid] = 0;
  rowcnt[tid + 256] = 0;
  __syncthreads();
  for (int i = s0 + tid; i < s1; i += 256)
    atomicAdd(&rowcnt[(tmp[i].x >> 17) & (BROWS - 1)], 1);
  __syncthreads();
  int c0 = rowcnt[2 * tid], c1 = rowcnt[2 * tid + 1];
  int tsum = c0 + c1;
  s[tid] = tsum;
  __syncthreads();
  for (int off = 1; off < 256; off <<= 1) {
    int x = (tid >= off) ? s[tid - off] : 0;
    __syncthreads();
    s[tid] += x;
    __syncthreads();
  }
  int excl = s0 + s[tid] - tsum;
  __syncthreads();
  rowptr[2 * tid] = excl;
  rowptr[2 * tid + 1] = excl + c0;
  int r0 = row0 + 2 * tid;
  if (r0 < n) offs[r0] = excl;
  if (r0 + 1 < n) offs[r0 + 1] = excl + c0;
  __syncthreads();
  for (int i = s0 + tid; i < s1; i += 256) {
    int2 eu = tmp[i];
    int rel = (eu.x >> 17) & (BROWS - 1);
    int slot = atomicAdd(&rowptr[rel], 1);
    csr[slot] = make_int2(eu.x & COLMASK, eu.y);
  }
}

// ---------------------------------------------------------------------------
// SpMM1 + bias + relu + dropout (bf16 gathers)
// ---------------------------------------------------------------------------
__global__ __launch_bounds__(256) void spmm1_kernel(const int* __restrict__ offs,
                                                    const int2* __restrict__ csr,
                                                    const __bf16* __restrict__ xwb,
                                                    const float* __restrict__ b1,
                                                    const float* __restrict__ dmask,
                                                    float* __restrict__ x2, int n) {
  const int lane = threadIdx.x & 63;
  const int wid = threadIdx.x >> 6;
  const int row = blockIdx.x * 4 + wid;
  if (row >= n) return;
  const int s = offs[row], t = offs[row + 1];
  const bf16x2* xw2 = (const bf16x2*)xwb;
  float ax = 0.f, ay = 0.f;
  int j = s;
  for (; j + 3 < t; j += 4) {
    int2 c0 = csr[j], c1 = csr[j + 1], c2 = csr[j + 2], c3 = csr[j + 3];
    bf16x2 v0 = xw2[(size_t)c0.x * 64 + lane];
    bf16x2 v1 = xw2[(size_t)c1.x * 64 + lane];
    bf16x2 v2 = xw2[(size_t)c2.x * 64 + lane];
    bf16x2 v3 = xw2[(size_t)c3.x * 64 + lane];
    float w0 = __int_as_float(c0.y), w1 = __int_as_float(c1.y);
    float w2 = __int_as_float(c2.y), w3 = __int_as_float(c3.y);
    ax += w0 * (float)v0[0] + w1 * (float)v1[0] + w2 * (float)v2[0] + w3 * (float)v3[0];
    ay += w0 * (float)v0[1] + w1 * (float)v1[1] + w2 * (float)v2[1] + w3 * (float)v3[1];
  }
  for (; j < t; ++j) {
    int2 c = csr[j];
    float w = __int_as_float(c.y);
    bf16x2 v = xw2[(size_t)c.x * 64 + lane];
    ax += w * (float)v[0];
    ay += w * (float)v[1];
  }
  const int f = lane * 2;
  float2 dm = ((const float2*)dmask)[row * 64 + lane];
  float h0 = fmaxf(ax + b1[f], 0.f) * dm.x;
  float h1 = fmaxf(ay + b1[f + 1], 0.f) * dm.y;
  ((float2*)x2)[row * 64 + lane] = make_float2(h0, h1);
}

// ---------------------------------------------------------------------------
// GEMM2: x2wb[n,40] = bf16(x2[n,128] @ W2[128,40])
// ---------------------------------------------------------------------------
__global__ __launch_bounds__(256) void gemm2_kernel(const float* __restrict__ x2,
                                                    const float* __restrict__ W2,
                                                    __bf16* __restrict__ x2wb, int n) {
  const int lane = threadIdx.x & 63;
  const int wid = threadIdx.x >> 6;
  const int row = blockIdx.x * 4 + wid;
  if (row >= n || lane >= NCLASS) return;
  const float4* xr4 = (const float4*)(x2 + (size_t)row * NHID);
  float acc = 0.f;
#pragma unroll 8
  for (int k4 = 0; k4 < NHID / 4; ++k4) {
    float4 a = xr4[k4];
    int k = k4 * 4;
    acc = fmaf(a.x, W2[(k + 0) * NCLASS + lane], acc);
    acc = fmaf(a.y, W2[(k + 1) * NCLASS + lane], acc);
    acc = fmaf(a.z, W2[(k + 2) * NCLASS + lane], acc);
    acc = fmaf(a.w, W2[(k + 3) * NCLASS + lane], acc);
  }
  x2wb[(size_t)row * NCLASS + lane] = (__bf16)acc;
}

// ---------------------------------------------------------------------------
// SpMM2 + bias (bf16 gathers)
// ---------------------------------------------------------------------------
__global__ __launch_bounds__(256) void spmm2_kernel(const int* __restrict__ offs,
                                                    const int2* __restrict__ csr,
                                                    const __bf16* __restrict__ x2wb,
                                                    const float* __restrict__ b2,
                                                    float* __restrict__ x3, int n) {
  const int lane = threadIdx.x & 63;
  const int wid = threadIdx.x >> 6;
  const int row = blockIdx.x * 4 + wid;
  if (row >= n || lane >= NCLASS) return;
  const int s = offs[row], t = offs[row + 1];
  float acc = 0.f;
  int j = s;
  for (; j + 3 < t; j += 4) {
    int2 c0 = csr[j], c1 = csr[j + 1], c2 = csr[j + 2], c3 = csr[j + 3];
    float g0 = (float)x2wb[(size_t)c0.x * NCLASS + lane];
    float g1 = (float)x2wb[(size_t)c1.x * NCLASS + lane];
    float g2 = (float)x2wb[(size_t)c2.x * NCLASS + lane];
    float g3 = (float)x2wb[(size_t)c3.x * NCLASS + lane];
    acc += __int_as_float(c0.y) * g0 + __int_as_float(c1.y) * g1 +
           __int_as_float(c2.y) * g2 + __int_as_float(c3.y) * g3;
  }
  for (; j < t; ++j) {
    int2 c = csr[j];
    acc += __int_as_float(c.y) * (float)x2wb[(size_t)c.x * NCLASS + lane];
  }
  x3[(size_t)row * NCLASS + lane] = acc + b2[lane];
}

// ---------------------------------------------------------------------------
// log_softmax in place over 40 classes
// ---------------------------------------------------------------------------
__global__ __launch_bounds__(256) void logsoftmax_kernel(float* __restrict__ x3, int n) {
  const int lane = threadIdx.x & 63;
  const int wid = threadIdx.x >> 6;
  const int row = blockIdx.x * 4 + wid;
  if (row >= n) return;
  float v = (lane < NCLASS) ? x3[(size_t)row * NCLASS + lane] : -__builtin_inff();
  float m = v;
#pragma unroll
  for (int off = 32; off > 0; off >>= 1) m = fmaxf(m, __shfl_xor(m, off, 64));
  float ex = (lane < NCLASS) ? expf(v - m) : 0.f;
  float ssum = ex;
#pragma unroll
  for (int off = 32; off > 0; off >>= 1) ssum += __shfl_xor(ssum, off, 64);
  if (lane < NCLASS) x3[(size_t)row * NCLASS + lane] = v - m - logf(ssum);
}

// ---------------------------------------------------------------------------
extern "C" void kernel_launch(void* const* d_in, const int* in_sizes, int n_in,
                              void* d_out, int out_size, void* d_ws, size_t ws_size,
                              hipStream_t stream) {
  const float* x = (const float*)d_in[0];
  const int* erow = (const int*)d_in[1];
  const int* ecol = (const int*)d_in[2];
  const float* ew = (const float*)d_in[3];
  const float* W1 = (const float*)d_in[4];
  const float* b1 = (const float*)d_in[5];
  const float* W2 = (const float*)d_in[6];
  const float* b2 = (const float*)d_in[7];
  const float* dmask = (const float*)d_in[8];

  const int n = in_sizes[0] / NFEAT;  // 100000
  const int e = in_sizes[1];          // 3200000
  const int nb2 = (n + BROWS - 1) >> BSH;  // 196 coarse buckets

  float* out_ls = (float*)d_out;             // [n,40]
  float* x2 = out_ls + (size_t)n * NCLASS;   // [n,128]

  // workspace layout (tmp aliases x2wb: tmp dead before gemm2 writes x2wb)
  uintptr_t p = (uintptr_t)d_ws;
  __bf16* xwb = (__bf16*)p;  p += (size_t)n * NHID * 2;      // 25.6 MB
  __bf16* Btb = (__bf16*)p;  p += (size_t)NHID * NFEAT * 2;  // 128 KB
  int2* csr = (int2*)p;      p += (size_t)e * 8;             // 25.6 MB
  int2* tmp = (int2*)p;      __bf16* x2wb = (__bf16*)p;
  p += (size_t)e * 8;                                        // 25.6 MB (shared)
  int* offs = (int*)p;       p += ((size_t)n + 1) * 4;
  int* bhist = (int*)p;      p += 256 * 4;
  int* bbase = (int*)p;      p += 257 * 4;
  int* bcur = (int*)p;       p += 256 * 4;

  hipMemsetAsync(bhist, 0, 256 * sizeof(int), stream);

  convW1_kernel<<<NFEAT * NHID / 256, 256, 0, stream>>>(W1, Btb);
  gemm1_mfma_kernel<<<(n + 63) / 64, 256, 0, stream>>>(x, Btb, xwb, n);

  hist_kernel<<<1024, 256, 0, stream>>>(erow, bhist, e, nb2);
  bucketscan_kernel<<<1, 256, 0, stream>>>(bhist, bbase, bcur, offs, n, e, nb2);
  partition_kernel<<<(e + PCHUNK - 1) / PCHUNK, 256, 0, stream>>>(erow, ecol, ew, bcur, tmp, e, nb2);
  scatter_kernel<<<nb2, 256, 0, stream>>>(bbase, tmp, csr, offs, n);

  spmm1_kernel<<<(n + 3) / 4, 256, 0, stream>>>(offs, csr, xwb, b1, dmask, x2, n);
  gemm2_kernel<<<(n + 3) / 4, 256, 0, stream>>>(x2, W2, x2wb, n);
  spmm2_kernel<<<(n + 3) / 4, 256, 0, stream>>>(offs, csr, x2wb, b2, out_ls, n);
  logsoftmax_kernel<<<(n + 3) / 4, 256, 0, stream>>>(out_ls, n);
}

// Round 5
// 754.974 us; speedup vs baseline: 1.8441x; 1.2734x over previous
//
#include <hip/hip_runtime.h>
#include <math.h>

#define NFEAT 512
#define NHID  128
#define NCLASS 40

// coarse bucket = 512 rows; col packed bits 0..16, rel-row bits 17..25
#define BSH 9
#define BROWS 512
#define COLMASK 0x1FFFF
#define PCHUNK 8192

typedef __bf16 bf16x8 __attribute__((ext_vector_type(8)));
typedef __bf16 bf16x4 __attribute__((ext_vector_type(4)));
typedef float f32x4 __attribute__((ext_vector_type(4)));

// ---------------------------------------------------------------------------
// W1 [512,128] f32 -> Bt [128,512] bf16 (transposed)
// ---------------------------------------------------------------------------
__global__ void convW1_kernel(const float* __restrict__ W1, __bf16* __restrict__ Bt) {
  int i = blockIdx.x * 256 + threadIdx.x;  // 65536
  int kk = i >> 7, nn = i & 127;
  Bt[nn * 512 + kk] = (__bf16)W1[i];
}

// W2 [128,40] f32 -> W2t [48,128] bf16 (transposed, zero-padded cols 40..47)
__global__ void convW2_kernel(const float* __restrict__ W2, __bf16* __restrict__ W2t) {
  int i = blockIdx.x * 256 + threadIdx.x;  // 6144
  int c = i >> 7, k = i & 127;
  W2t[i] = (c < NCLASS) ? (__bf16)W2[k * NCLASS + c] : (__bf16)0.f;
}

// ---------------------------------------------------------------------------
// GEMM1 (tiled MFMA bf16): xwb[n,128] = bf16(X[n,512] @ W1)
// ---------------------------------------------------------------------------
#define ASTR 48
#define BSTR 48
__global__ __launch_bounds__(256) void gemm1_mfma_kernel(const float* __restrict__ X,
                                                         const __bf16* __restrict__ Bt,
                                                         __bf16* __restrict__ xwb, int n) {
  __shared__ __bf16 smem[64 * ASTR + 128 * BSTR];
  __bf16* As = smem;
  __bf16* Bs = smem + 64 * ASTR;

  const int tid = threadIdx.x;
  const int lane = tid & 63;
  const int wid = tid >> 6;
  const int m = lane & 15;
  const int quad = lane >> 4;
  const int row0 = blockIdx.x * 64;

  f32x4 acc[8];
#pragma unroll
  for (int t = 0; t < 8; ++t) acc[t] = (f32x4){0.f, 0.f, 0.f, 0.f};

  const int ar = tid >> 3, aq = tid & 7;
  const int bc = tid >> 2, bq = tid & 3;

  const float4* X4 = (const float4*)X;
  const bf16x8* Bt8 = (const bf16x8*)Bt;
  const float4 z4 = make_float4(0.f, 0.f, 0.f, 0.f);
  const int r1 = row0 + ar, r2 = row0 + 32 + ar;
  const bool ok1 = r1 < n, ok2 = r2 < n;

  float4 a0, a1;
  bf16x8 b0, b1;
  a0 = ok1 ? X4[(size_t)r1 * 128 + aq] : z4;
  a1 = ok2 ? X4[(size_t)r2 * 128 + aq] : z4;
  b0 = Bt8[(size_t)bc * 64 + bq];
  b1 = Bt8[(size_t)(64 + bc) * 64 + bq];

  for (int kt = 0; kt < 16; ++kt) {
    __syncthreads();
    bf16x4 av0, av1;
    av0[0] = (__bf16)a0.x; av0[1] = (__bf16)a0.y; av0[2] = (__bf16)a0.z; av0[3] = (__bf16)a0.w;
    av1[0] = (__bf16)a1.x; av1[1] = (__bf16)a1.y; av1[2] = (__bf16)a1.z; av1[3] = (__bf16)a1.w;
    *(bf16x4*)&As[ar * ASTR + aq * 4] = av0;
    *(bf16x4*)&As[(32 + ar) * ASTR + aq * 4] = av1;
    *(bf16x8*)&Bs[bc * BSTR + bq * 8] = b0;
    *(bf16x8*)&Bs[(64 + bc) * BSTR + bq * 8] = b1;
    __syncthreads();
    if (kt < 15) {
      int ko = (kt + 1) * 8, kc = (kt + 1) * 4;
      a0 = ok1 ? X4[(size_t)r1 * 128 + ko + aq] : z4;
      a1 = ok2 ? X4[(size_t)r2 * 128 + ko + aq] : z4;
      b0 = Bt8[(size_t)bc * 64 + kc + bq];
      b1 = Bt8[(size_t)(64 + bc) * 64 + kc + bq];
    }
    bf16x8 af = *(const bf16x8*)&As[(wid * 16 + m) * ASTR + quad * 8];
#pragma unroll
    for (int t = 0; t < 8; ++t) {
      bf16x8 bfr = *(const bf16x8*)&Bs[(t * 16 + m) * BSTR + quad * 8];
      acc[t] = __builtin_amdgcn_mfma_f32_16x16x32_bf16(af, bfr, acc[t], 0, 0, 0);
    }
  }

  __syncthreads();
  __bf16* cs = smem;  // [64][136]
#pragma unroll
  for (int t = 0; t < 8; ++t)
#pragma unroll
    for (int r = 0; r < 4; ++r)
      cs[(wid * 16 + quad * 4 + r) * 136 + t * 16 + m] = (__bf16)acc[t][r];
  __syncthreads();
  bf16x8* xwv = (bf16x8*)xwb;
#pragma unroll
  for (int i = 0; i < 4; ++i) {
    int p = tid + i * 256;
    int r = p >> 4, c8 = p & 15;
    int gr = row0 + r;
    if (gr < n) xwv[(size_t)gr * 16 + c8] = *(const bf16x8*)&cs[r * 136 + c8 * 8];
  }
}

// ---------------------------------------------------------------------------
// CSR build pass 0: coarse-bucket histogram (LDS-aggregated)
// ---------------------------------------------------------------------------
__global__ __launch_bounds__(256) void hist_kernel(const int* __restrict__ erow,
                                                   int* __restrict__ bhist, int e, int nb2) {
  __shared__ int h[256];
  const int tid = threadIdx.x;
  h[tid] = 0;
  __syncthreads();
  for (int i = blockIdx.x * 256 + tid; i < e; i += gridDim.x * 256)
    atomicAdd(&h[erow[i] >> BSH], 1);
  __syncthreads();
  if (tid < nb2 && h[tid]) atomicAdd(&bhist[tid], h[tid]);
}

// pass 1: scan bucket totals (single block)
__global__ __launch_bounds__(256) void bucketscan_kernel(const int* __restrict__ bhist,
                                                         int* __restrict__ bbase,
                                                         int* __restrict__ bcur,
                                                         int* __restrict__ offs,
                                                         int n, int e, int nb2) {
  __shared__ int s[256];
  const int tid = threadIdx.x;
  int v = (tid < nb2) ? bhist[tid] : 0;
  s[tid] = v;
  __syncthreads();
  for (int off = 1; off < 256; off <<= 1) {
    int x = (tid >= off) ? s[tid - off] : 0;
    __syncthreads();
    s[tid] += x;
    __syncthreads();
  }
  int excl = s[tid] - v;
  if (tid <= nb2) bbase[tid] = excl;
  if (tid < nb2) bcur[tid] = excl;
  if (tid == 0) offs[n] = e;
}

// pass 2: chunked counting-sort partition (grouped writes)
__global__ __launch_bounds__(256) void partition_kernel(const int* __restrict__ erow,
                                                        const int* __restrict__ ecol,
                                                        const float* __restrict__ ew,
                                                        int* __restrict__ bcur,
                                                        int2* __restrict__ tmp, int e, int nb2) {
  __shared__ int hist[256];
  __shared__ int base[256];
  const int tid = threadIdx.x;
  const int b0 = blockIdx.x * PCHUNK;
  hist[tid] = 0;
  int pk[32], meta[32];
  __syncthreads();
#pragma unroll
  for (int i = 0; i < 32; ++i) {
    int idx = b0 + i * 256 + tid;
    if (idx < e) {
      int r = erow[idx];
      int c = ecol[idx];
      int bk = r >> BSH;
      int rk = atomicAdd(&hist[bk], 1);
      pk[i] = c | ((r & (BROWS - 1)) << 17);
      meta[i] = bk | (rk << 8);
    } else {
      meta[i] = -1;
    }
  }
  __syncthreads();
  if (tid < nb2 && hist[tid]) base[tid] = atomicAdd(&bcur[tid], hist[tid]);
  __syncthreads();
#pragma unroll
  for (int i = 0; i < 32; ++i) {
    if (meta[i] >= 0) {
      int bk = meta[i] & 255, rk = meta[i] >> 8;
      int idx = b0 + i * 256 + tid;
      tmp[base[bk] + rk] = make_int2(pk[i], __float_as_int(ew[idx]));
    }
  }
}

// pass 3: one block per coarse bucket -> offs + final CSR
__global__ __launch_bounds__(256) void scatter_kernel(const int* __restrict__ bbase,
                                                      const int2* __restrict__ tmp,
                                                      int2* __restrict__ csr,
                                                      int* __restrict__ offs, int n) {
  __shared__ int rowcnt[BROWS];
  __shared__ int rowptr[BROWS];
  __shared__ int s[256];
  const int b = blockIdx.x, tid = threadIdx.x;
  const int row0 = b << BSH;
  const int s0 = bbase[b], s1 = bbase[b + 1];
  rowcnt[tid] = 0;
  rowcnt[tid + 256] = 0;
  __syncthreads();
  for (int i = s0 + tid; i < s1; i += 256)
    atomicAdd(&rowcnt[(tmp[i].x >> 17) & (BROWS - 1)], 1);
  __syncthreads();
  int c0 = rowcnt[2 * tid], c1 = rowcnt[2 * tid + 1];
  int tsum = c0 + c1;
  s[tid] = tsum;
  __syncthreads();
  for (int off = 1; off < 256; off <<= 1) {
    int x = (tid >= off) ? s[tid - off] : 0;
    __syncthreads();
    s[tid] += x;
    __syncthreads();
  }
  int excl = s0 + s[tid] - tsum;
  __syncthreads();
  rowptr[2 * tid] = excl;
  rowptr[2 * tid + 1] = excl + c0;
  int r0 = row0 + 2 * tid;
  if (r0 < n) offs[r0] = excl;
  if (r0 + 1 < n) offs[r0 + 1] = excl + c0;
  __syncthreads();
  for (int i = s0 + tid; i < s1; i += 256) {
    int2 eu = tmp[i];
    int rel = (eu.x >> 17) & (BROWS - 1);
    int slot = atomicAdd(&rowptr[rel], 1);
    csr[slot] = make_int2(eu.x & COLMASK, eu.y);
  }
}

// ---------------------------------------------------------------------------
// SpMM1 + bias + relu + dropout: 2 edges per wave-instruction (bf16x4 lanes)
// ---------------------------------------------------------------------------
__global__ __launch_bounds__(256) void spmm1_kernel(const int* __restrict__ offs,
                                                    const int2* __restrict__ csr,
                                                    const __bf16* __restrict__ xwb,
                                                    const float* __restrict__ b1,
                                                    const float* __restrict__ dmask,
                                                    float* __restrict__ x2, int n) {
  const int lane = threadIdx.x & 63;
  const int wid = threadIdx.x >> 6;
  const int row = blockIdx.x * 4 + wid;
  if (row >= n) return;
  const int s = offs[row], t = offs[row + 1];
  const int half = lane >> 5, sl = lane & 31;
  const bf16x4* xv = (const bf16x4*)xwb;  // row stride 32 chunks
  float a0 = 0.f, a1 = 0.f, a2 = 0.f, a3 = 0.f;
  int j = s;
  for (; j + 3 < t; j += 4) {  // 4 edges: 2 unguarded gathers in flight/lane
    int2 ca = csr[j + half];
    int2 cb = csr[j + 2 + half];
    bf16x4 va = xv[(size_t)ca.x * 32 + sl];
    bf16x4 vb = xv[(size_t)cb.x * 32 + sl];
    float wa = __int_as_float(ca.y), wb = __int_as_float(cb.y);
    a0 += wa * (float)va[0] + wb * (float)vb[0];
    a1 += wa * (float)va[1] + wb * (float)vb[1];
    a2 += wa * (float)va[2] + wb * (float)vb[2];
    a3 += wa * (float)va[3] + wb * (float)vb[3];
  }
  for (; j < t; j += 2) {
    int jj = j + half;
    bool ok = jj < t;
    int2 c = csr[ok ? jj : j];
    float w = ok ? __int_as_float(c.y) : 0.f;
    bf16x4 v = xv[(size_t)c.x * 32 + sl];
    a0 += w * (float)v[0];
    a1 += w * (float)v[1];
    a2 += w * (float)v[2];
    a3 += w * (float)v[3];
  }
  a0 += __shfl_xor(a0, 32); a1 += __shfl_xor(a1, 32);
  a2 += __shfl_xor(a2, 32); a3 += __shfl_xor(a3, 32);
  if (half == 0) {
    float4 bb = ((const float4*)b1)[sl];
    float4 dm = ((const float4*)dmask)[(size_t)row * 32 + sl];
    float4 o;
    o.x = fmaxf(a0 + bb.x, 0.f) * dm.x;
    o.y = fmaxf(a1 + bb.y, 0.f) * dm.y;
    o.z = fmaxf(a2 + bb.z, 0.f) * dm.z;
    o.w = fmaxf(a3 + bb.w, 0.f) * dm.w;
    ((float4*)x2)[(size_t)row * 32 + sl] = o;
  }
}

// ---------------------------------------------------------------------------
// GEMM2 (MFMA bf16): x2wb[n,64pad] = bf16(x2[n,128] @ W2[128,40])
// whole K=128 in LDS; B-frags register-resident from W2t (L2-hot)
// ---------------------------------------------------------------------------
#define A2STR 136
__global__ __launch_bounds__(256) void gemm2_mfma_kernel(const float* __restrict__ x2,
                                                         const __bf16* __restrict__ W2t,
                                                         __bf16* __restrict__ x2wb, int n) {
  __shared__ __bf16 As[64 * A2STR];  // 17408 B
  const int tid = threadIdx.x;
  const int lane = tid & 63;
  const int wid = tid >> 6;
  const int m = lane & 15;
  const int quad = lane >> 4;
  const int row0 = blockIdx.x * 64;

  const bf16x8* Bv = (const bf16x8*)W2t;  // [48][16]
  bf16x8 bfr[3][4];
#pragma unroll
  for (int t = 0; t < 3; ++t)
#pragma unroll
    for (int ks = 0; ks < 4; ++ks)
      bfr[t][ks] = Bv[(t * 16 + m) * 16 + ks * 4 + quad];

  const float4* X4 = (const float4*)x2;  // row stride 32
  const float4 z4 = make_float4(0.f, 0.f, 0.f, 0.f);
#pragma unroll
  for (int i = 0; i < 8; ++i) {
    int p = tid + i * 256;  // 2048 float4 chunks = 64 rows x 32
    int r = p >> 5, q = p & 31;
    int gr = row0 + r;
    float4 a = (gr < n) ? X4[(size_t)gr * 32 + q] : z4;
    bf16x4 av;
    av[0] = (__bf16)a.x; av[1] = (__bf16)a.y; av[2] = (__bf16)a.z; av[3] = (__bf16)a.w;
    *(bf16x4*)&As[r * A2STR + q * 4] = av;
  }
  __syncthreads();

  f32x4 acc[3];
#pragma unroll
  for (int t = 0; t < 3; ++t) acc[t] = (f32x4){0.f, 0.f, 0.f, 0.f};
#pragma unroll
  for (int ks = 0; ks < 4; ++ks) {
    bf16x8 af = *(const bf16x8*)&As[(wid * 16 + m) * A2STR + ks * 32 + quad * 8];
#pragma unroll
    for (int t = 0; t < 3; ++t)
      acc[t] = __builtin_amdgcn_mfma_f32_16x16x32_bf16(af, bfr[t][ks], acc[t], 0, 0, 0);
  }
  __syncthreads();

  // epilogue: LDS bounce [64][64], zero cols 48..63
  __bf16* cs = As;
  {
    bf16x4 z;
    z[0] = z[1] = z[2] = z[3] = (__bf16)0.f;
    *(bf16x4*)&cs[(tid >> 2) * 64 + 48 + (tid & 3) * 4] = z;
  }
#pragma unroll
  for (int t = 0; t < 3; ++t)
#pragma unroll
    for (int r = 0; r < 4; ++r)
      cs[(wid * 16 + quad * 4 + r) * 64 + t * 16 + m] = (__bf16)acc[t][r];
  __syncthreads();
  bf16x8* ov = (bf16x8*)x2wb;  // row stride 8 chunks (128 B)
#pragma unroll
  for (int i = 0; i < 2; ++i) {
    int p = tid + i * 256;  // 512 chunks
    int r = p >> 3, c8 = p & 7;
    int gr = row0 + r;
    if (gr < n) ov[(size_t)gr * 8 + c8] = *(const bf16x8*)&cs[r * 64 + c8 * 8];
  }
}

// ---------------------------------------------------------------------------
// SpMM2 + bias + fused log_softmax: 4 edges per wave-instruction
// x2wb rows padded to 64 bf16 = 128 B = one L2 line per edge gather
// ---------------------------------------------------------------------------
__global__ __launch_bounds__(256) void spmm2_kernel(const int* __restrict__ offs,
                                                    const int2* __restrict__ csr,
                                                    const __bf16* __restrict__ x2wb,
                                                    const float* __restrict__ b2,
                                                    float* __restrict__ out, int n) {
  const int lane = threadIdx.x & 63;
  const int wid = threadIdx.x >> 6;
  const int row = blockIdx.x * 4 + wid;
  if (row >= n) return;
  const int s = offs[row], t = offs[row + 1];
  const int grp = lane >> 4, sl = lane & 15;
  const bf16x4* xv = (const bf16x4*)x2wb;  // row stride 16 chunks
  float a0 = 0.f, a1 = 0.f, a2 = 0.f, a3 = 0.f;
  int j = s;
  for (; j + 7 < t; j += 8) {  // 8 edges: 2 unguarded gathers in flight/lane
    int2 ca = csr[j + grp];
    int2 cb = csr[j + 4 + grp];
    bf16x4 va = xv[(size_t)ca.x * 16 + sl];
    bf16x4 vb = xv[(size_t)cb.x * 16 + sl];
    float wa = __int_as_float(ca.y), wb = __int_as_float(cb.y);
    a0 += wa * (float)va[0] + wb * (float)vb[0];
    a1 += wa * (float)va[1] + wb * (float)vb[1];
    a2 += wa * (float)va[2] + wb * (float)vb[2];
    a3 += wa * (float)va[3] + wb * (float)vb[3];
  }
  for (; j < t; j += 4) {
    int jj = j + grp;
    bool ok = jj < t;
    int2 c = csr[ok ? jj : j];
    float w = ok ? __int_as_float(c.y) : 0.f;
    bf16x4 v = xv[(size_t)c.x * 16 + sl];
    a0 += w * (float)v[0];
    a1 += w * (float)v[1];
    a2 += w * (float)v[2];
    a3 += w * (float)v[3];
  }
  a0 += __shfl_xor(a0, 16); a1 += __shfl_xor(a1, 16);
  a2 += __shfl_xor(a2, 16); a3 += __shfl_xor(a3, 16);
  a0 += __shfl_xor(a0, 32); a1 += __shfl_xor(a1, 32);
  a2 += __shfl_xor(a2, 32); a3 += __shfl_xor(a3, 32);

  // fused log_softmax over 40 classes (lanes sl<10 hold 4 valid classes each)
  const float NINF = -__builtin_inff();
  float l0 = NINF, l1 = NINF, l2 = NINF, l3 = NINF;
  if (sl < 10) {
    float4 bb = ((const float4*)b2)[sl];
    l0 = a0 + bb.x; l1 = a1 + bb.y; l2 = a2 + bb.z; l3 = a3 + bb.w;
  }
  float mx = fmaxf(fmaxf(l0, l1), fmaxf(l2, l3));
#pragma unroll
  for (int off = 8; off > 0; off >>= 1) mx = fmaxf(mx, __shfl_xor(mx, off));
  float es = 0.f;
  if (sl < 10) es = expf(l0 - mx) + expf(l1 - mx) + expf(l2 - mx) + expf(l3 - mx);
#pragma unroll
  for (int off = 8; off > 0; off >>= 1) es += __shfl_xor(es, off);
  if (grp == 0 && sl < 10) {
    float lg = mx + logf(es);
    float4 o = make_float4(l0 - lg, l1 - lg, l2 - lg, l3 - lg);
    ((float4*)out)[(size_t)row * 10 + sl] = o;
  }
}

// ---------------------------------------------------------------------------
extern "C" void kernel_launch(void* const* d_in, const int* in_sizes, int n_in,
                              void* d_out, int out_size, void* d_ws, size_t ws_size,
                              hipStream_t stream) {
  const float* x = (const float*)d_in[0];
  const int* erow = (const int*)d_in[1];
  const int* ecol = (const int*)d_in[2];
  const float* ew = (const float*)d_in[3];
  const float* W1 = (const float*)d_in[4];
  const float* b1 = (const float*)d_in[5];
  const float* W2 = (const float*)d_in[6];
  const float* b2 = (const float*)d_in[7];
  const float* dmask = (const float*)d_in[8];

  const int n = in_sizes[0] / NFEAT;       // 100000
  const int e = in_sizes[1];               // 3200000
  const int nb2 = (n + BROWS - 1) >> BSH;  // 196 coarse buckets

  float* out_ls = (float*)d_out;            // [n,40]
  float* x2 = out_ls + (size_t)n * NCLASS;  // [n,128]

  // workspace layout (x2wb aliases tmp: tmp dead before gemm2 writes x2wb)
  uintptr_t p = (uintptr_t)d_ws;
  __bf16* xwb = (__bf16*)p;  p += (size_t)n * NHID * 2;      // 25.6 MB
  __bf16* Btb = (__bf16*)p;  p += (size_t)NHID * NFEAT * 2;  // 128 KB
  __bf16* W2t = (__bf16*)p;  p += (size_t)48 * NHID * 2;     // 12 KB
  int2* csr = (int2*)p;      p += (size_t)e * 8;             // 25.6 MB
  int2* tmp = (int2*)p;      __bf16* x2wb = (__bf16*)p;      // pad-64 rows
  p += (size_t)e * 8;                                        // 25.6 MB (shared)
  int* offs = (int*)p;       p += ((size_t)n + 1) * 4;
  int* bhist = (int*)p;      p += 256 * 4;
  int* bbase = (int*)p;      p += 257 * 4;
  int* bcur = (int*)p;       p += 256 * 4;

  hipMemsetAsync(bhist, 0, 256 * sizeof(int), stream);

  convW1_kernel<<<NFEAT * NHID / 256, 256, 0, stream>>>(W1, Btb);
  convW2_kernel<<<48 * NHID / 256, 256, 0, stream>>>(W2, W2t);
  gemm1_mfma_kernel<<<(n + 63) / 64, 256, 0, stream>>>(x, Btb, xwb, n);

  hist_kernel<<<1024, 256, 0, stream>>>(erow, bhist, e, nb2);
  bucketscan_kernel<<<1, 256, 0, stream>>>(bhist, bbase, bcur, offs, n, e, nb2);
  partition_kernel<<<(e + PCHUNK - 1) / PCHUNK, 256, 0, stream>>>(erow, ecol, ew, bcur, tmp, e, nb2);
  scatter_kernel<<<nb2, 256, 0, stream>>>(bbase, tmp, csr, offs, n);

  spmm1_kernel<<<(n + 3) / 4, 256, 0, stream>>>(offs, csr, xwb, b1, dmask, x2, n);
  gemm2_mfma_kernel<<<(n + 63) / 64, 256, 0, stream>>>(x2, W2t, x2wb, n);
  spmm2_kernel<<<(n + 3) / 4, 256, 0, stream>>>(offs, csr, x2wb, b2, out_ls, n);
}